// Round 4
// baseline (268.431 us; speedup 1.0000x reference)
//
#include <hip/hip_runtime.h>

typedef unsigned short u16;
typedef unsigned int u32;
typedef __attribute__((ext_vector_type(8))) short short8;
typedef __attribute__((ext_vector_type(4))) float f32x4;

#define NATOMS 8000
#define MNBR 12
#define EPSV 1e-5f
#define AB 4
#define ROWS 48

// stage buffer geometry: 12 groups of 4 edges; group = 4*256B data + 32B pad
#define GRP_B 1056
#define STG_B 12672  // 12 * GRP_B
__device__ __forceinline__ int stg_idx(int row, int col) {  // u16 index
  return (row >> 2) * 528 + (row & 3) * 128 + col;
}

// ---- ws layout (bytes) ----
#define PA_OFF 0                         // u16 PA[8000][768]
#define WTA_OFF 12288000                 // u16 WtAtom[768][64]
#define WTE_OFF 12386304                 // u16 WtEdge[512][64]
#define STATS_OFF 12451840               // f32 stats[1792]
#define PARAMS_OFF 12459008              // f32 params[768]
#define TBUF_OFF 12462080                // f32 tbuf[8000*64]
#define WS_NEED 14510080

// stats layout (f32 indices)
#define ST_BN1S 0
#define ST_BN1S2 128
#define ST_BNES 256
#define ST_BNES2 384
#define ST_A 512
#define ST_A2 640
#define ST_U2 768
#define ST_V2 896
#define ST_UB 1024
#define ST_VB 1152
#define ST_AU 1280
#define ST_AV 1408
#define ST_UV 1536
#define ST_BN2S 1664
#define ST_BN2S2 1728

__device__ __forceinline__ u16 f2bf(float f) {
  u32 u = __float_as_uint(f);
  u += 0x7FFFu + ((u >> 16) & 1u);
  return (u16)(u >> 16);
}
__device__ __forceinline__ float bf2f(u16 h) { return __uint_as_float(((u32)h) << 16); }

__device__ __forceinline__ float sigf(float x) {
  return __builtin_amdgcn_rcpf(1.f + __expf(-x));
}
__device__ __forceinline__ float spf(float x) {
  return fmaxf(x, 0.f) + __logf(1.f + __expf(-fabsf(x)));
}

__device__ __forceinline__ void mfma16(f32x4 &acc, short8 a, short8 b) {
  asm volatile("v_mfma_f32_16x16x32_bf16 %0, %1, %2, %0" : "+v"(acc) : "v"(a), "v"(b));
}
__device__ __forceinline__ void accfence(f32x4 &a) {
  asm volatile("s_nop 7\ns_nop 7\ns_nop 7" : "+v"(a));
}
__device__ __forceinline__ void initfence(f32x4 &a) {
  asm volatile("s_nop 1" : "+v"(a));
}

typedef __attribute__((address_space(3))) unsigned int lds_uint;
typedef __attribute__((address_space(1))) const unsigned int glob_uint;
__device__ __forceinline__ void dma16(const void* g, void* l) {
  __builtin_amdgcn_global_load_lds((glob_uint*)g, (lds_uint*)l, 16, 0, 0);
}

// gather two 48x128 PA column-slices into stage A/B (padded-group layout)
__device__ __forceinline__ void dma_pj2(const u16* __restrict__ PA, const int* __restrict__ nidx,
                                        int eb, char* stA, char* stB, int off0, int off1,
                                        int w, int l) {
#pragma unroll
  for (int i = 0; i < 3; ++i) {
    int gg = w * 3 + i;
    int ai = nidx[eb + gg * 4 + (l >> 4)];
    const u16* base = PA + (size_t)ai * 768 + ((l & 15) << 3);
    dma16(base + off0, (u16*)stA + gg * 528);
    dma16(base + off1, (u16*)stB + gg * 528);
  }
}
__device__ __forceinline__ void dma_own2(const u16* __restrict__ PA, u16* paown0, u16* paown1,
                                         int ab, int l) {
  const u16* src = PA + (size_t)(ab + (l >> 4)) * 768 + ((l & 15) << 3);
  dma16(src, paown0);
  dma16(src + 256, paown1);
}

// stage 16 f32 -> 16 bf16 into XOR-swizzled LDS row (row stride 128B)
__device__ __forceinline__ void stage_row16(short* lds, int row, int c16, const float* __restrict__ src) {
  const float4* s4 = reinterpret_cast<const float4*>(src);
  float4 q0 = s4[0], q1 = s4[1], q2 = s4[2], q3 = s4[3];
  short8 lo, hi;
  lo[0]=(short)f2bf(q0.x); lo[1]=(short)f2bf(q0.y); lo[2]=(short)f2bf(q0.z); lo[3]=(short)f2bf(q0.w);
  lo[4]=(short)f2bf(q1.x); lo[5]=(short)f2bf(q1.y); lo[6]=(short)f2bf(q1.z); lo[7]=(short)f2bf(q1.w);
  hi[0]=(short)f2bf(q2.x); hi[1]=(short)f2bf(q2.y); hi[2]=(short)f2bf(q2.z); hi[3]=(short)f2bf(q2.w);
  hi[4]=(short)f2bf(q3.x); hi[5]=(short)f2bf(q3.y); hi[6]=(short)f2bf(q3.z); hi[7]=(short)f2bf(q3.w);
  int base = row * 128 + c16 * 2;
  int sw = (row & 7) << 4;
  *reinterpret_cast<short8*>(reinterpret_cast<char*>(lds) + (base ^ sw)) = lo;
  *reinterpret_cast<short8*>(reinterpret_cast<char*>(lds) + ((base + 16) ^ sw)) = hi;
}

__device__ __forceinline__ short8 lds_afrag(const short* lds, int row, int kbyte) {
  int off = (row * 128 + kbyte) ^ ((row & 7) << 4);
  return *reinterpret_cast<const short8*>(reinterpret_cast<const char*>(lds) + off);
}

// MFMA step: E-block (48 edges x 128 cols), wave w owns col-tiles {w, w+4}
template <int RT>
__device__ __forceinline__ void mfma_block(const short* nbrT, const u16* __restrict__ WTE,
                                           int b, int w, int l, f32x4 (&acc)[RT][2]) {
  short8 bfr[2][2];
#pragma unroll
  for (int p = 0; p < 2; ++p) {
    int wr = b * 128 + ((w + p * 4) << 4) + (l & 15);
#pragma unroll
    for (int kc = 0; kc < 2; ++kc)
      bfr[p][kc] = *reinterpret_cast<const short8*>(WTE + (size_t)wr * 64 + kc * 32 + ((l >> 4) << 3));
  }
#pragma unroll
  for (int rt = 0; rt < RT; ++rt)
#pragma unroll
    for (int p = 0; p < 2; ++p) { acc[rt][p] = f32x4{0.f, 0.f, 0.f, 0.f}; initfence(acc[rt][p]); }
#pragma unroll
  for (int rt = 0; rt < RT; ++rt) {
    int arow = rt * 16 + (l & 15);
    short8 a0 = lds_afrag(nbrT, arow, (l >> 4) << 4);
    short8 a1 = lds_afrag(nbrT, arow, 64 + ((l >> 4) << 4));
#pragma unroll
    for (int p = 0; p < 2; ++p) {
      mfma16(acc[rt][p], a0, bfr[p][0]);
      mfma16(acc[rt][p], a1, bfr[p][1]);
    }
  }
#pragma unroll
  for (int rt = 0; rt < RT; ++rt)
#pragma unroll
    for (int p = 0; p < 2; ++p) accfence(acc[rt][p]);
}

// ---------------- K0: transpose weights to bf16 [col][k] + zero stats ----------------
__global__ __launch_bounds__(256) void k0_prep(const float* __restrict__ W_full,
                                               const float* __restrict__ W_edge,
                                               const float* __restrict__ W_3body,
                                               u16* __restrict__ WTA, u16* __restrict__ WTE,
                                               float* __restrict__ stats) {
  int t = blockIdx.x * 256 + threadIdx.x;
  if (t < 1792) stats[t] = 0.f;
  if (t < 49152) {  // WtAtom: 768 cols x 64 k
    int col = t >> 6, k = t & 63;
    int blk = col >> 7, c = col & 127;
    float v;
    switch (blk) {
      case 0: v = W_full[k * 128 + c]; break;
      case 1: v = W_full[(64 + k) * 128 + c]; break;
      case 2: v = W_edge[k * 128 + c]; break;
      case 3: v = W_edge[(64 + k) * 128 + c]; break;
      case 4: v = W_3body[(64 + k) * 128 + c]; break;
      default: v = W_3body[(128 + k) * 128 + c]; break;
    }
    WTA[t] = f2bf(v);
  } else if (t < 49152 + 32768) {  // WtEdge: 512 cols x 64 k
    int u = t - 49152;
    int col = u >> 6, k = u & 63;
    int blk = col >> 7, c = col & 127;
    float v;
    switch (blk) {
      case 0: v = W_full[(128 + k) * 128 + c]; break;
      case 1: v = W_edge[(128 + k) * 128 + c]; break;
      case 2: v = W_3body[(192 + k) * 128 + c]; break;
      default: v = W_3body[(256 + k) * 128 + c]; break;
    }
    WTE[u] = f2bf(v);
  }
}

// ---------------- K1: PA = atom_in @ [W1|W2|We1|We2|Wj|Wl]  (bf16 table) ----------------
__global__ __launch_bounds__(256) void k1_pa(const float* __restrict__ atom_in,
                                             const u16* __restrict__ WTA,
                                             u16* __restrict__ PA) {
  __shared__ __align__(16) short xt[16 * 64];
  int t = threadIdx.x, l = t & 63, w = t >> 6;
  int ab = blockIdx.x * 16;
  if (t < 64) {
    int row = t >> 2, c16 = (t & 3) * 16;
    stage_row16(xt, row, c16, atom_in + (size_t)(ab + row) * 64 + c16);
  }
  __syncthreads();
  short8 a0 = lds_afrag(xt, l & 15, (l >> 4) << 4);
  short8 a1 = lds_afrag(xt, l & 15, 64 + ((l >> 4) << 4));
  for (int q = 0; q < 12; ++q) {
    int colg = (w * 12 + q) * 16 + (l & 15);
    short8 b0 = *reinterpret_cast<const short8*>(WTA + (size_t)colg * 64 + ((l >> 4) << 3));
    short8 b1 = *reinterpret_cast<const short8*>(WTA + (size_t)colg * 64 + 32 + ((l >> 4) << 3));
    f32x4 acc = f32x4{0.f, 0.f, 0.f, 0.f};
    initfence(acc);
    mfma16(acc, a0, b0);
    mfma16(acc, a1, b1);
    accfence(acc);
#pragma unroll
    for (int r = 0; r < 4; ++r) {
      int row = ((l >> 4) << 2) + r;
      PA[(size_t)(ab + row) * 768 + colg] = f2bf(acc[r]);
    }
  }
}

// ---------------- K2a: bn1/bne statistics (b = 0,1) ----------------
__global__ __launch_bounds__(256, 4) void k2a_stats(const float* __restrict__ nbr_fea,
                                                    const int* __restrict__ nidx,
                                                    const float* __restrict__ b_full,
                                                    const float* __restrict__ b_edge,
                                                    const u16* __restrict__ PA,
                                                    const u16* __restrict__ WTE,
                                                    float* __restrict__ stats) {
  __shared__ __align__(16) char smem[33536];
  short* nbrT = (short*)smem;                 // 6144
  u16* paown0 = (u16*)(smem + 31488);
  u16* paown1 = (u16*)(smem + 32512);
  int t = threadIdx.x, l = t & 63, w = t >> 6;
  int ab = blockIdx.x * AB, eb = ab * 12;

  dma_pj2(PA, nidx, eb, smem + 6144, smem + 18816, 128, 384, w, l);
  if (w == 0) dma_own2(PA, paown0, paown1, ab, l);
  for (int u = t; u < ROWS * 4; u += 256) {
    int row = u >> 2, c16 = (u & 3) * 16;
    stage_row16(nbrT, row, c16, nbr_fea + (size_t)(eb + row) * 64 + c16);
  }
  __syncthreads();

#pragma unroll
  for (int b = 0; b < 2; ++b) {
    const u16* stg = (const u16*)(smem + 6144 + b * STG_B);
    const u16* po = b ? paown1 : paown0;
    f32x4 acc[3][2];
    mfma_block<3>(nbrT, WTE, b, w, l, acc);
    int col0 = (w << 4) + (l & 15), col1 = col0 + 64;
    int g = l >> 4;
    const float* bp = b ? b_edge : b_full;
    float bias0 = bp[col0], bias1 = bp[col1];
    float vs0 = 0.f, vs1 = 0.f, q0 = 0.f, q1 = 0.f;
#pragma unroll
    for (int rt = 0; rt < 3; ++rt) {
      int a12 = (rt * 16 + g * 4) / 12;
      float o0 = bf2f(po[a12 * 128 + col0]) + bias0;
      float o1 = bf2f(po[a12 * 128 + col1]) + bias1;
#pragma unroll
      for (int r = 0; r < 4; ++r) {
        int row = rt * 16 + g * 4 + r;
        float v0 = acc[rt][0][r] + bf2f(stg[stg_idx(row, col0)]) + o0;
        float v1 = acc[rt][1][r] + bf2f(stg[stg_idx(row, col1)]) + o1;
        vs0 += v0; q0 += v0 * v0; vs1 += v1; q1 += v1 * v1;
      }
    }
    vs0 += __shfl_xor(vs0, 16); vs0 += __shfl_xor(vs0, 32);
    vs1 += __shfl_xor(vs1, 16); vs1 += __shfl_xor(vs1, 32);
    q0 += __shfl_xor(q0, 16); q0 += __shfl_xor(q0, 32);
    q1 += __shfl_xor(q1, 16); q1 += __shfl_xor(q1, 32);
    if (l < 16) {
      int base = b ? ST_BNES : ST_BN1S;
      atomicAdd(&stats[base + col0], vs0);
      atomicAdd(&stats[base + 128 + col0], q0);
      atomicAdd(&stats[base + col1], vs1);
      atomicAdd(&stats[base + 128 + col1], q1);
    }
  }
}

// ---------------- K2b: u/v stats (b = 2,3) + analytic bn3 sums ----------------
__global__ __launch_bounds__(256, 4) void k2b_stats(const float* __restrict__ atom_in,
                                                    const float* __restrict__ nbr_fea,
                                                    const int* __restrict__ nidx,
                                                    const float* __restrict__ W_3body,
                                                    const float* __restrict__ b_3body,
                                                    const u16* __restrict__ PA,
                                                    const u16* __restrict__ WTE,
                                                    float* __restrict__ stats) {
  __shared__ __align__(16) char smem[36608];
  short* nbrT   = (short*)smem;                 // 6144
  float* ubar   = (float*)(smem + 31488);       // 2048
  float* vbar   = (float*)(smem + 33536);       // 2048
  float* xown   = (float*)(smem + 35584);       // 1024
  float* redscr = (float*)(smem + 6144);        // alias stageA (epilogue only)
  int t = threadIdx.x, l = t & 63, w = t >> 6;
  int ab = blockIdx.x * AB, eb = ab * 12;

  dma_pj2(PA, nidx, eb, smem + 6144, smem + 18816, 512, 640, w, l);
  for (int u = t; u < ROWS * 4; u += 256) {
    int row = u >> 2, c16 = (u & 3) * 16;
    stage_row16(nbrT, row, c16, nbr_fea + (size_t)(eb + row) * 64 + c16);
  }
  ubar[t] = 0.f; ubar[256 + t] = 0.f; vbar[t] = 0.f; vbar[256 + t] = 0.f;
  xown[t] = atom_in[(size_t)ab * 64 + t];
  __syncthreads();

#pragma unroll
  for (int b = 2; b < 4; ++b) {
    const u16* stg = (const u16*)(smem + 6144 + (b - 2) * STG_B);
    float* uvb = (b == 2) ? ubar : vbar;
    f32x4 acc[3][2];
    mfma_block<3>(nbrT, WTE, b, w, l, acc);
    int col0 = (w << 4) + (l & 15), col1 = col0 + 64;
    int g = l >> 4;
    float q0 = 0.f, q1 = 0.f;
#pragma unroll
    for (int rt = 0; rt < 3; ++rt) {
      int a12 = (rt * 16 + g * 4) / 12;
      float s0 = 0.f, s1 = 0.f;
#pragma unroll
      for (int r = 0; r < 4; ++r) {
        int row = rt * 16 + g * 4 + r;
        float v0 = acc[rt][0][r] + bf2f(stg[stg_idx(row, col0)]);
        float v1 = acc[rt][1][r] + bf2f(stg[stg_idx(row, col1)]);
        s0 += v0; q0 += v0 * v0; s1 += v1; q1 += v1 * v1;
      }
      atomicAdd(&uvb[a12 * 128 + col0], s0);
      atomicAdd(&uvb[a12 * 128 + col1], s1);
    }
    q0 += __shfl_xor(q0, 16); q0 += __shfl_xor(q0, 32);
    q1 += __shfl_xor(q1, 16); q1 += __shfl_xor(q1, 32);
    if (l < 16) {
      int sb = (b == 2) ? ST_U2 : ST_V2;
      atomicAdd(&stats[sb + col0], q0);
      atomicAdd(&stats[sb + col1], q1);
    }
  }
  __syncthreads();

  // analytic bn3 sums
  {
    int c = t & 127, h = t >> 7;
    float dv0 = 0.f, dv1 = 0.f;
    for (int k = 0; k < 64; ++k) {
      float wk = W_3body[k * 128 + c];
      dv0 += xown[(2 * h) * 64 + k] * wk;
      dv1 += xown[(2 * h + 1) * 64 + k] * wk;
    }
    float b3v = b_3body[c];
    float pA = 0.f, pA2 = 0.f, pUb = 0.f, pVb = 0.f, pAU = 0.f, pAV = 0.f, pUV = 0.f;
#pragma unroll
    for (int aa = 0; aa < 2; ++aa) {
      int a = 2 * h + aa;
      float aval = (aa ? dv1 : dv0) + b3v;
      float ub = ubar[a * 128 + c] * (1.f / 12.f);
      float vb = vbar[a * 128 + c] * (1.f / 12.f);
      pA += aval; pA2 += aval * aval; pUb += ub; pVb += vb;
      pAU += aval * ub; pAV += aval * vb; pUV += ub * vb;
    }
    if (h == 1) {
      float* rs = &redscr[c * 7];
      rs[0] = pA; rs[1] = pA2; rs[2] = pUb; rs[3] = pVb; rs[4] = pAU; rs[5] = pAV; rs[6] = pUV;
    }
    __syncthreads();
    if (h == 0) {
      const float* rs = &redscr[c * 7];
      atomicAdd(&stats[ST_A + c], pA + rs[0]);
      atomicAdd(&stats[ST_A2 + c], pA2 + rs[1]);
      atomicAdd(&stats[ST_UB + c], pUb + rs[2]);
      atomicAdd(&stats[ST_VB + c], pVb + rs[3]);
      atomicAdd(&stats[ST_AU + c], pAU + rs[4]);
      atomicAdd(&stats[ST_AV + c], pAV + rs[5]);
      atomicAdd(&stats[ST_UV + c], pUV + rs[6]);
    }
  }
}

// ---------------- K3: finalize bn1/bne/bn3 affine params ----------------
__global__ void k3_params(const float* __restrict__ stats,
                          const float* __restrict__ g1, const float* __restrict__ be1,
                          const float* __restrict__ ge, const float* __restrict__ bee,
                          const float* __restrict__ g3, const float* __restrict__ be3,
                          float* __restrict__ params) {
  int c = threadIdx.x;
  if (c >= 128) return;
  const float cnt1 = 1.f / 96000.f;
  {
    float m = stats[ST_BN1S + c] * cnt1;
    float var = stats[ST_BN1S2 + c] * cnt1 - m * m;
    float s = g1[c] * rsqrtf(fmaxf(var, 0.f) + EPSV);
    params[c] = s; params[128 + c] = be1[c] - m * s;
  }
  {
    float m = stats[ST_BNES + c] * cnt1;
    float var = stats[ST_BNES2 + c] * cnt1 - m * m;
    float s = ge[c] * rsqrtf(fmaxf(var, 0.f) + EPSV);
    params[256 + c] = s; params[384 + c] = bee[c] - m * s;
  }
  {
    float Nf = (float)NATOMS;
    float A_ = stats[ST_A + c], A2 = stats[ST_A2 + c];
    float U2 = stats[ST_U2 + c], V2 = stats[ST_V2 + c];
    float Ub = stats[ST_UB + c], Vb = stats[ST_VB + c];
    float AU = stats[ST_AU + c], AV = stats[ST_AV + c], UV = stats[ST_UV + c];
    float m = (A_ + Ub + Vb) / Nf;
    float ez2 = A2 / Nf + (U2 + V2) / (Nf * 12.f) + 2.f * (AU + AV + UV) / Nf;
    float var = ez2 - m * m;
    float s = g3[c] * rsqrtf(fmaxf(var, 0.f) + EPSV);
    params[512 + c] = s; params[640 + c] = be3[c] - m * s;
  }
}

// ---------------- K4a: gates (b = 0,1) -> tbuf (two-body) + out_nbr ----------------
__global__ __launch_bounds__(256, 4) void k4a_main(const float* __restrict__ nbr_fea,
                                                   const int* __restrict__ nidx,
                                                   const float* __restrict__ b_full,
                                                   const float* __restrict__ b_edge,
                                                   const u16* __restrict__ PA,
                                                   const u16* __restrict__ WTE,
                                                   const float* __restrict__ params,
                                                   float* __restrict__ tbuf,
                                                   float* __restrict__ out_nbr) {
  __shared__ __align__(16) char smem[36608];
  short* nbrT     = (short*)smem;                 // 6144
  u16* paown0     = (u16*)(smem + 31488);
  u16* paown1     = (u16*)(smem + 32512);
  float* t2buf    = (float*)(smem + 33536);       // 1024
  float* params_s = (float*)(smem + 34560);       // 2048
  int t = threadIdx.x, l = t & 63, w = t >> 6;
  int ab = blockIdx.x * AB, eb = ab * 12;

  dma_pj2(PA, nidx, eb, smem + 6144, smem + 18816, 128, 384, w, l);
  if (w == 0) dma_own2(PA, paown0, paown1, ab, l);
  for (int u = t; u < ROWS * 4; u += 256) {
    int row = u >> 2, c16 = (u & 3) * 16;
    stage_row16(nbrT, row, c16, nbr_fea + (size_t)(eb + row) * 64 + c16);
  }
  params_s[t] = params[t];
  params_s[t + 256] = params[t + 256];
  t2buf[t] = 0.f;
  __syncthreads();

#pragma unroll
  for (int b = 0; b < 2; ++b) {
    const u16* stg = (const u16*)(smem + 6144 + b * STG_B);
    const u16* po = b ? paown1 : paown0;
    f32x4 acc[3][2];
    mfma_block<3>(nbrT, WTE, b, w, l, acc);
    int col0 = (w << 4) + (l & 15), col1 = col0 + 64;
    int g = l >> 4;
    const float* bp = b ? b_edge : b_full;
    float bias0 = bp[col0], bias1 = bp[col1];
    float sc0 = params_s[b * 256 + col0], sh0 = params_s[b * 256 + 128 + col0];
    float sc1 = params_s[b * 256 + col1], sh1 = params_s[b * 256 + 128 + col1];
#pragma unroll
    for (int rt = 0; rt < 3; ++rt) {
      int a12 = (rt * 16 + g * 4) / 12;
      float o0 = bf2f(po[a12 * 128 + col0]) + bias0;
      float o1 = bf2f(po[a12 * 128 + col1]) + bias1;
      float gsum = 0.f;
#pragma unroll
      for (int r = 0; r < 4; ++r) {
        int row = rt * 16 + g * 4 + r;
        float v0 = acc[rt][0][r] + bf2f(stg[stg_idx(row, col0)]) + o0;
        float v1 = acc[rt][1][r] + bf2f(stg[stg_idx(row, col1)]) + o1;
        float gate = sigf(v0 * sc0 + sh0) * spf(v1 * sc1 + sh1);
        if (b == 0) {
          gsum += gate;
        } else {
          size_t eg = (size_t)(eb + row) * 64 + col0;
          out_nbr[eg] = nbr_fea[eg] + gate;
        }
      }
      if (b == 0) atomicAdd(&t2buf[a12 * 64 + col0], gsum);
    }
  }
  __syncthreads();
  tbuf[(size_t)(ab + w) * 64 + l] = t2buf[t];
}

// ---------------- K4b: 3-body (b = 2,3) + bn2 stats ----------------
__global__ __launch_bounds__(256, 4) void k4b_main(const float* __restrict__ atom_in,
                                                   const float* __restrict__ nbr_fea,
                                                   const int* __restrict__ nidx,
                                                   const float* __restrict__ W_3body,
                                                   const float* __restrict__ b_3body,
                                                   const u16* __restrict__ PA,
                                                   const u16* __restrict__ WTE,
                                                   const float* __restrict__ params,
                                                   float* __restrict__ tbuf,
                                                   float* __restrict__ stats) {
  __shared__ __align__(16) char smem[35584];
  short* nbrT    = (short*)smem;                 // 6144
  u16* stage2    = (u16*)(smem + 6144);
  u16* stage3    = (u16*)(smem + 18816);
  float* a_s     = (float*)(smem + 31488);       // 2048
  float* xown    = (float*)(smem + 33536);       // 1024
  float* p3_s    = (float*)(smem + 34560);       // 1024: s3[0:128) t3[128:256)
  float* redscr2 = (float*)(smem + 6144);        // alias stage2 (final phase only)
  int t = threadIdx.x, l = t & 63, w = t >> 6;
  int ab = blockIdx.x * AB, eb = ab * 12;

  dma_pj2(PA, nidx, eb, smem + 6144, smem + 18816, 512, 640, w, l);
  for (int u = t; u < ROWS * 4; u += 256) {
    int row = u >> 2, c16 = (u & 3) * 16;
    stage_row16(nbrT, row, c16, nbr_fea + (size_t)(eb + row) * 64 + c16);
  }
  xown[t] = atom_in[(size_t)ab * 64 + t];
  p3_s[t] = params[512 + t];
  float two_body = tbuf[(size_t)(ab + w) * 64 + l];
  __syncthreads();

  // a' = (x_i @ Wa + b3) * s3 + t3 (f32)
  {
    int c = t & 127, h = t >> 7;
    float dv0 = 0.f, dv1 = 0.f;
    for (int k = 0; k < 64; ++k) {
      float wk = W_3body[k * 128 + c];
      dv0 += xown[(2 * h) * 64 + k] * wk;
      dv1 += xown[(2 * h + 1) * 64 + k] * wk;
    }
    float s3 = p3_s[c], t3 = p3_s[128 + c];
    float b3v = b_3body[c];
    a_s[(2 * h) * 128 + c] = (dv0 + b3v) * s3 + t3;
    a_s[(2 * h + 1) * 128 + c] = (dv1 + b3v) * s3 + t3;
  }

#pragma unroll
  for (int b = 2; b < 4; ++b) {
    u16* stg = (b == 2) ? stage2 : stage3;
    f32x4 acc[3][2];
    mfma_block<3>(nbrT, WTE, b, w, l, acc);
    int col0 = (w << 4) + (l & 15), col1 = col0 + 64;
    int g = l >> 4;
    float s30 = p3_s[col0], s31 = p3_s[col1];
#pragma unroll
    for (int rt = 0; rt < 3; ++rt) {
#pragma unroll
      for (int r = 0; r < 4; ++r) {
        int row = rt * 16 + g * 4 + r;
        float v0 = (acc[rt][0][r] + bf2f(stg[stg_idx(row, col0)])) * s30;
        float v1 = (acc[rt][1][r] + bf2f(stg[stg_idx(row, col1)])) * s31;
        stg[stg_idx(row, col0)] = f2bf(v0);
        stg[stg_idx(row, col1)] = f2bf(v1);
      }
    }
  }
  __syncthreads();

  // 3-body via exp factorization: sig(a+u+v) = rcp(1+E*F), sp = ln2*log2(1+G*H)
  float acc3 = 0.f;
  {
    int c = l, a = w;
    float af = a_s[a * 128 + c], ac = a_s[a * 128 + 64 + c];
    float Fl[12], Hl[12];
#pragma unroll
    for (int j2 = 0; j2 < 12; ++j2) {
      float vf = bf2f(stage3[stg_idx(a * 12 + j2, c)]);
      float vc = bf2f(stage3[stg_idx(a * 12 + j2, 64 + c)]);
      Fl[j2] = __expf(-vf);
      Hl[j2] = __expf(vc);
    }
    for (int j = 0; j < 12; ++j) {
      float uf = bf2f(stage2[stg_idx(a * 12 + j, c)]);
      float uc = bf2f(stage2[stg_idx(a * 12 + j, 64 + c)]);
      float Ej = __expf(-(af + uf));
      float Gj = __expf(ac + uc);
#pragma unroll
      for (int l2 = 0; l2 < 12; ++l2) {
        float p = fmaf(Ej, Fl[l2], 1.f);
        float q = fmaf(Gj, Hl[l2], 1.f);
        acc3 += __builtin_amdgcn_rcpf(p) * __log2f(q);
      }
    }
  }
  __syncthreads();

  // t = two + three body; bn2 partial sums
  {
    float x = two_body + acc3 * 0.6931471805599453f;
    tbuf[(size_t)(ab + w) * 64 + l] = x;
    redscr2[t] = x;
    redscr2[256 + t] = x * x;
    __syncthreads();
    if (t < 64) {
      float s = redscr2[t] + redscr2[t + 64] + redscr2[t + 128] + redscr2[t + 192];
      float s2 = redscr2[256 + t] + redscr2[256 + t + 64] + redscr2[256 + t + 128] + redscr2[256 + t + 192];
      atomicAdd(&stats[ST_BN2S + t], s);
      atomicAdd(&stats[ST_BN2S2 + t], s2);
    }
  }
}

// ---------------- K6: bn2 + final softplus ----------------
__global__ __launch_bounds__(256) void k6_out(const float* __restrict__ atom_in,
                                              const float* __restrict__ tbuf,
                                              const float* __restrict__ stats,
                                              const float* __restrict__ g2,
                                              const float* __restrict__ be2,
                                              float* __restrict__ out_atom) {
  __shared__ float sc[64], sh[64];
  int t = threadIdx.x;
  if (t < 64) {
    float S = stats[ST_BN2S + t], S2 = stats[ST_BN2S2 + t];
    float m = S * (1.f / (float)NATOMS);
    float var = S2 * (1.f / (float)NATOMS) - m * m;
    float s = g2[t] * rsqrtf(fmaxf(var, 0.f) + EPSV);
    sc[t] = s; sh[t] = be2[t] - m * s;
  }
  __syncthreads();
  int i = blockIdx.x * 256 + t;
  if (i < NATOMS * 64) {
    int c = i & 63;
    float v = atom_in[i] + tbuf[i] * sc[c] + sh[c];
    out_atom[i] = spf(v);
  }
}

extern "C" void kernel_launch(void* const* d_in, const int* in_sizes, int n_in,
                              void* d_out, int out_size, void* d_ws, size_t ws_size,
                              hipStream_t stream) {
  if (ws_size < (size_t)WS_NEED) return;
  const float* atom_in = (const float*)d_in[0];
  const float* nbr_fea = (const float*)d_in[1];
  const int* nidx = (const int*)d_in[2];
  const float* W_full = (const float*)d_in[3];
  const float* b_full = (const float*)d_in[4];
  const float* g1 = (const float*)d_in[5];
  const float* be1 = (const float*)d_in[6];
  const float* W_edge = (const float*)d_in[7];
  const float* b_edge = (const float*)d_in[8];
  const float* ge = (const float*)d_in[9];
  const float* bee = (const float*)d_in[10];
  const float* W_3body = (const float*)d_in[11];
  const float* b_3body = (const float*)d_in[12];
  const float* g3 = (const float*)d_in[13];
  const float* be3 = (const float*)d_in[14];
  const float* g2 = (const float*)d_in[15];
  const float* be2 = (const float*)d_in[16];

  char* ws = (char*)d_ws;
  u16* PA = (u16*)(ws + PA_OFF);
  u16* WTA = (u16*)(ws + WTA_OFF);
  u16* WTE = (u16*)(ws + WTE_OFF);
  float* stats = (float*)(ws + STATS_OFF);
  float* params = (float*)(ws + PARAMS_OFF);
  float* tbuf = (float*)(ws + TBUF_OFF);

  float* out_atom = (float*)d_out;
  float* out_nbr = out_atom + NATOMS * 64;

  k0_prep<<<320, 256, 0, stream>>>(W_full, W_edge, W_3body, WTA, WTE, stats);
  k1_pa<<<500, 256, 0, stream>>>(atom_in, WTA, PA);
  k2a_stats<<<2000, 256, 0, stream>>>(nbr_fea, nidx, b_full, b_edge, PA, WTE, stats);
  k2b_stats<<<2000, 256, 0, stream>>>(atom_in, nbr_fea, nidx, W_3body, b_3body, PA, WTE, stats);
  k3_params<<<1, 128, 0, stream>>>(stats, g1, be1, ge, bee, g3, be3, params);
  k4a_main<<<2000, 256, 0, stream>>>(nbr_fea, nidx, b_full, b_edge, PA, WTE, params, tbuf, out_nbr);
  k4b_main<<<2000, 256, 0, stream>>>(atom_in, nbr_fea, nidx, W_3body, b_3body, PA, WTE, params,
                                     tbuf, stats);
  k6_out<<<2000, 256, 0, stream>>>(atom_in, tbuf, stats, g2, be2, out_atom);
}

// Round 5
// 168.601 us; speedup vs baseline: 1.5921x; 1.5921x over previous
//
#include <hip/hip_runtime.h>

typedef unsigned short u16;
typedef unsigned int u32;
typedef __attribute__((ext_vector_type(8))) short short8;
typedef __attribute__((ext_vector_type(4))) float f32x4;

#define NATOMS 8000
#define MNBR 12
#define EPSV 1e-5f
#define AB 4
#define ROWS 48
#define REPL 16
#define STATSN 1792

// stage buffer geometry: 12 groups of 4 edges; group = 4*256B data + 32B pad
#define GRP_B 1056
#define STG_B 12672  // 12 * GRP_B
__device__ __forceinline__ int stg_idx(int row, int col) {  // u16 index
  return (row >> 2) * 528 + (row & 3) * 128 + col;
}

// ---- ws layout (bytes) ----
#define PA_OFF 0                         // u16 PA[8000][768]
#define WTA_OFF 12288000                 // u16 WtAtom[768][64]
#define WTE_OFF 12386304                 // u16 WtEdge[512][64]
#define STATS_OFF 12451840               // f32 stats[REPL][1792]
#define PARAMS_OFF 12566528              // f32 params[768]
#define TBUF_OFF 12569600                // f32 tbuf[8000*64]
#define WS_NEED 14617600

// stats layout (f32 indices, per replica)
#define ST_BN1S 0
#define ST_BN1S2 128
#define ST_BNES 256
#define ST_BNES2 384
#define ST_A 512
#define ST_A2 640
#define ST_U2 768
#define ST_V2 896
#define ST_UB 1024
#define ST_VB 1152
#define ST_AU 1280
#define ST_AV 1408
#define ST_UV 1536
#define ST_BN2S 1664
#define ST_BN2S2 1728

__device__ __forceinline__ u16 f2bf(float f) {
  u32 u = __float_as_uint(f);
  u += 0x7FFFu + ((u >> 16) & 1u);
  return (u16)(u >> 16);
}
__device__ __forceinline__ float bf2f(u16 h) { return __uint_as_float(((u32)h) << 16); }

__device__ __forceinline__ float sigf(float x) {
  return __builtin_amdgcn_rcpf(1.f + __expf(-x));
}
__device__ __forceinline__ float spf(float x) {
  return fmaxf(x, 0.f) + __logf(1.f + __expf(-fabsf(x)));
}

__device__ __forceinline__ void mfma16(f32x4 &acc, short8 a, short8 b) {
  asm volatile("v_mfma_f32_16x16x32_bf16 %0, %1, %2, %0" : "+v"(acc) : "v"(a), "v"(b));
}
__device__ __forceinline__ void accfence(f32x4 &a) {
  asm volatile("s_nop 7\ns_nop 7\ns_nop 7" : "+v"(a));
}
__device__ __forceinline__ void initfence(f32x4 &a) {
  asm volatile("s_nop 1" : "+v"(a));
}

typedef __attribute__((address_space(3))) unsigned int lds_uint;
typedef __attribute__((address_space(1))) const unsigned int glob_uint;
__device__ __forceinline__ void dma16(const void* g, void* l) {
  __builtin_amdgcn_global_load_lds((glob_uint*)g, (lds_uint*)l, 16, 0, 0);
}

// gather two 48x128 PA column-slices into stage A/B (padded-group layout)
__device__ __forceinline__ void dma_pj2(const u16* __restrict__ PA, const int* __restrict__ nidx,
                                        int eb, char* stA, char* stB, int off0, int off1,
                                        int w, int l) {
#pragma unroll
  for (int i = 0; i < 3; ++i) {
    int gg = w * 3 + i;
    int ai = nidx[eb + gg * 4 + (l >> 4)];
    const u16* base = PA + (size_t)ai * 768 + ((l & 15) << 3);
    dma16(base + off0, (u16*)stA + gg * 528);
    dma16(base + off1, (u16*)stB + gg * 528);
  }
}
__device__ __forceinline__ void dma_own2(const u16* __restrict__ PA, u16* paown0, u16* paown1,
                                         int ab, int l) {
  const u16* src = PA + (size_t)(ab + (l >> 4)) * 768 + ((l & 15) << 3);
  dma16(src, paown0);
  dma16(src + 256, paown1);
}

// stage 16 f32 -> 16 bf16 into XOR-swizzled LDS row (row stride 128B)
__device__ __forceinline__ void stage_row16(short* lds, int row, int c16, const float* __restrict__ src) {
  const float4* s4 = reinterpret_cast<const float4*>(src);
  float4 q0 = s4[0], q1 = s4[1], q2 = s4[2], q3 = s4[3];
  short8 lo, hi;
  lo[0]=(short)f2bf(q0.x); lo[1]=(short)f2bf(q0.y); lo[2]=(short)f2bf(q0.z); lo[3]=(short)f2bf(q0.w);
  lo[4]=(short)f2bf(q1.x); lo[5]=(short)f2bf(q1.y); lo[6]=(short)f2bf(q1.z); lo[7]=(short)f2bf(q1.w);
  hi[0]=(short)f2bf(q2.x); hi[1]=(short)f2bf(q2.y); hi[2]=(short)f2bf(q2.z); hi[3]=(short)f2bf(q2.w);
  hi[4]=(short)f2bf(q3.x); hi[5]=(short)f2bf(q3.y); hi[6]=(short)f2bf(q3.z); hi[7]=(short)f2bf(q3.w);
  int base = row * 128 + c16 * 2;
  int sw = (row & 7) << 4;
  *reinterpret_cast<short8*>(reinterpret_cast<char*>(lds) + (base ^ sw)) = lo;
  *reinterpret_cast<short8*>(reinterpret_cast<char*>(lds) + ((base + 16) ^ sw)) = hi;
}

__device__ __forceinline__ short8 lds_afrag(const short* lds, int row, int kbyte) {
  int off = (row * 128 + kbyte) ^ ((row & 7) << 4);
  return *reinterpret_cast<const short8*>(reinterpret_cast<const char*>(lds) + off);
}

// MFMA step: E-block (48 edges x 128 cols), wave w owns col-tiles {w, w+4}
template <int RT>
__device__ __forceinline__ void mfma_block(const short* nbrT, const u16* __restrict__ WTE,
                                           int b, int w, int l, f32x4 (&acc)[RT][2]) {
  short8 bfr[2][2];
#pragma unroll
  for (int p = 0; p < 2; ++p) {
    int wr = b * 128 + ((w + p * 4) << 4) + (l & 15);
#pragma unroll
    for (int kc = 0; kc < 2; ++kc)
      bfr[p][kc] = *reinterpret_cast<const short8*>(WTE + (size_t)wr * 64 + kc * 32 + ((l >> 4) << 3));
  }
#pragma unroll
  for (int rt = 0; rt < RT; ++rt)
#pragma unroll
    for (int p = 0; p < 2; ++p) { acc[rt][p] = f32x4{0.f, 0.f, 0.f, 0.f}; initfence(acc[rt][p]); }
#pragma unroll
  for (int rt = 0; rt < RT; ++rt) {
    int arow = rt * 16 + (l & 15);
    short8 a0 = lds_afrag(nbrT, arow, (l >> 4) << 4);
    short8 a1 = lds_afrag(nbrT, arow, 64 + ((l >> 4) << 4));
#pragma unroll
    for (int p = 0; p < 2; ++p) {
      mfma16(acc[rt][p], a0, bfr[p][0]);
      mfma16(acc[rt][p], a1, bfr[p][1]);
    }
  }
#pragma unroll
  for (int rt = 0; rt < RT; ++rt)
#pragma unroll
    for (int p = 0; p < 2; ++p) accfence(acc[rt][p]);
}

// ---------------- K0: transpose weights to bf16 [col][k] + zero stats replicas ----------------
__global__ __launch_bounds__(256) void k0_prep(const float* __restrict__ W_full,
                                               const float* __restrict__ W_edge,
                                               const float* __restrict__ W_3body,
                                               u16* __restrict__ WTA, u16* __restrict__ WTE,
                                               float* __restrict__ stats) {
  int t = blockIdx.x * 256 + threadIdx.x;
  if (t < REPL * STATSN) stats[t] = 0.f;
  if (t < 49152) {  // WtAtom: 768 cols x 64 k
    int col = t >> 6, k = t & 63;
    int blk = col >> 7, c = col & 127;
    float v;
    switch (blk) {
      case 0: v = W_full[k * 128 + c]; break;
      case 1: v = W_full[(64 + k) * 128 + c]; break;
      case 2: v = W_edge[k * 128 + c]; break;
      case 3: v = W_edge[(64 + k) * 128 + c]; break;
      case 4: v = W_3body[(64 + k) * 128 + c]; break;
      default: v = W_3body[(128 + k) * 128 + c]; break;
    }
    WTA[t] = f2bf(v);
  } else if (t < 49152 + 32768) {  // WtEdge: 512 cols x 64 k
    int u = t - 49152;
    int col = u >> 6, k = u & 63;
    int blk = col >> 7, c = col & 127;
    float v;
    switch (blk) {
      case 0: v = W_full[(128 + k) * 128 + c]; break;
      case 1: v = W_edge[(128 + k) * 128 + c]; break;
      case 2: v = W_3body[(192 + k) * 128 + c]; break;
      default: v = W_3body[(256 + k) * 128 + c]; break;
    }
    WTE[u] = f2bf(v);
  }
}

// ---------------- K1: PA = atom_in @ [W1|W2|We1|We2|Wj|Wl]  (bf16 table) ----------------
__global__ __launch_bounds__(256) void k1_pa(const float* __restrict__ atom_in,
                                             const u16* __restrict__ WTA,
                                             u16* __restrict__ PA) {
  __shared__ __align__(16) short xt[16 * 64];
  int t = threadIdx.x, l = t & 63, w = t >> 6;
  int ab = blockIdx.x * 16;
  if (t < 64) {
    int row = t >> 2, c16 = (t & 3) * 16;
    stage_row16(xt, row, c16, atom_in + (size_t)(ab + row) * 64 + c16);
  }
  __syncthreads();
  short8 a0 = lds_afrag(xt, l & 15, (l >> 4) << 4);
  short8 a1 = lds_afrag(xt, l & 15, 64 + ((l >> 4) << 4));
  for (int q = 0; q < 12; ++q) {
    int colg = (w * 12 + q) * 16 + (l & 15);
    short8 b0 = *reinterpret_cast<const short8*>(WTA + (size_t)colg * 64 + ((l >> 4) << 3));
    short8 b1 = *reinterpret_cast<const short8*>(WTA + (size_t)colg * 64 + 32 + ((l >> 4) << 3));
    f32x4 acc = f32x4{0.f, 0.f, 0.f, 0.f};
    initfence(acc);
    mfma16(acc, a0, b0);
    mfma16(acc, a1, b1);
    accfence(acc);
#pragma unroll
    for (int r = 0; r < 4; ++r) {
      int row = ((l >> 4) << 2) + r;
      PA[(size_t)(ab + row) * 768 + colg] = f2bf(acc[r]);
    }
  }
}

// ---------------- K2a: bn1/bne statistics (b = 0,1) ----------------
__global__ __launch_bounds__(256, 4) void k2a_stats(const float* __restrict__ nbr_fea,
                                                    const int* __restrict__ nidx,
                                                    const float* __restrict__ b_full,
                                                    const float* __restrict__ b_edge,
                                                    const u16* __restrict__ PA,
                                                    const u16* __restrict__ WTE,
                                                    float* __restrict__ stats_r) {
  __shared__ __align__(16) char smem[33536];
  short* nbrT = (short*)smem;                 // 6144
  u16* paown0 = (u16*)(smem + 31488);
  u16* paown1 = (u16*)(smem + 32512);
  int t = threadIdx.x, l = t & 63, w = t >> 6;
  int ab = blockIdx.x * AB, eb = ab * 12;
  float* stats = stats_r + (size_t)(blockIdx.x & (REPL - 1)) * STATSN;

  dma_pj2(PA, nidx, eb, smem + 6144, smem + 18816, 128, 384, w, l);
  if (w == 0) dma_own2(PA, paown0, paown1, ab, l);
  for (int u = t; u < ROWS * 4; u += 256) {
    int row = u >> 2, c16 = (u & 3) * 16;
    stage_row16(nbrT, row, c16, nbr_fea + (size_t)(eb + row) * 64 + c16);
  }
  __syncthreads();

#pragma unroll
  for (int b = 0; b < 2; ++b) {
    const u16* stg = (const u16*)(smem + 6144 + b * STG_B);
    const u16* po = b ? paown1 : paown0;
    f32x4 acc[3][2];
    mfma_block<3>(nbrT, WTE, b, w, l, acc);
    int col0 = (w << 4) + (l & 15), col1 = col0 + 64;
    int g = l >> 4;
    const float* bp = b ? b_edge : b_full;
    float bias0 = bp[col0], bias1 = bp[col1];
    float vs0 = 0.f, vs1 = 0.f, q0 = 0.f, q1 = 0.f;
#pragma unroll
    for (int rt = 0; rt < 3; ++rt) {
      int a12 = (rt * 16 + g * 4) / 12;
      float o0 = bf2f(po[a12 * 128 + col0]) + bias0;
      float o1 = bf2f(po[a12 * 128 + col1]) + bias1;
#pragma unroll
      for (int r = 0; r < 4; ++r) {
        int row = rt * 16 + g * 4 + r;
        float v0 = acc[rt][0][r] + bf2f(stg[stg_idx(row, col0)]) + o0;
        float v1 = acc[rt][1][r] + bf2f(stg[stg_idx(row, col1)]) + o1;
        vs0 += v0; q0 += v0 * v0; vs1 += v1; q1 += v1 * v1;
      }
    }
    vs0 += __shfl_xor(vs0, 16); vs0 += __shfl_xor(vs0, 32);
    vs1 += __shfl_xor(vs1, 16); vs1 += __shfl_xor(vs1, 32);
    q0 += __shfl_xor(q0, 16); q0 += __shfl_xor(q0, 32);
    q1 += __shfl_xor(q1, 16); q1 += __shfl_xor(q1, 32);
    if (l < 16) {
      int base = b ? ST_BNES : ST_BN1S;
      atomicAdd(&stats[base + col0], vs0);
      atomicAdd(&stats[base + 128 + col0], q0);
      atomicAdd(&stats[base + col1], vs1);
      atomicAdd(&stats[base + 128 + col1], q1);
    }
  }
}

// ---------------- K2b: u/v stats (b = 2,3) + analytic bn3 sums ----------------
__global__ __launch_bounds__(256, 4) void k2b_stats(const float* __restrict__ atom_in,
                                                    const float* __restrict__ nbr_fea,
                                                    const int* __restrict__ nidx,
                                                    const float* __restrict__ W_3body,
                                                    const float* __restrict__ b_3body,
                                                    const u16* __restrict__ PA,
                                                    const u16* __restrict__ WTE,
                                                    float* __restrict__ stats_r) {
  __shared__ __align__(16) char smem[36608];
  short* nbrT   = (short*)smem;                 // 6144
  float* ubar   = (float*)(smem + 31488);       // 2048
  float* vbar   = (float*)(smem + 33536);       // 2048
  float* xown   = (float*)(smem + 35584);       // 1024
  float* redscr = (float*)(smem + 6144);        // alias stageA (epilogue only)
  int t = threadIdx.x, l = t & 63, w = t >> 6;
  int ab = blockIdx.x * AB, eb = ab * 12;
  float* stats = stats_r + (size_t)(blockIdx.x & (REPL - 1)) * STATSN;

  dma_pj2(PA, nidx, eb, smem + 6144, smem + 18816, 512, 640, w, l);
  for (int u = t; u < ROWS * 4; u += 256) {
    int row = u >> 2, c16 = (u & 3) * 16;
    stage_row16(nbrT, row, c16, nbr_fea + (size_t)(eb + row) * 64 + c16);
  }
  ubar[t] = 0.f; ubar[256 + t] = 0.f; vbar[t] = 0.f; vbar[256 + t] = 0.f;
  xown[t] = atom_in[(size_t)ab * 64 + t];
  __syncthreads();

#pragma unroll
  for (int b = 2; b < 4; ++b) {
    const u16* stg = (const u16*)(smem + 6144 + (b - 2) * STG_B);
    float* uvb = (b == 2) ? ubar : vbar;
    f32x4 acc[3][2];
    mfma_block<3>(nbrT, WTE, b, w, l, acc);
    int col0 = (w << 4) + (l & 15), col1 = col0 + 64;
    int g = l >> 4;
    float q0 = 0.f, q1 = 0.f;
#pragma unroll
    for (int rt = 0; rt < 3; ++rt) {
      int a12 = (rt * 16 + g * 4) / 12;
      float s0 = 0.f, s1 = 0.f;
#pragma unroll
      for (int r = 0; r < 4; ++r) {
        int row = rt * 16 + g * 4 + r;
        float v0 = acc[rt][0][r] + bf2f(stg[stg_idx(row, col0)]);
        float v1 = acc[rt][1][r] + bf2f(stg[stg_idx(row, col1)]);
        s0 += v0; q0 += v0 * v0; s1 += v1; q1 += v1 * v1;
      }
      atomicAdd(&uvb[a12 * 128 + col0], s0);
      atomicAdd(&uvb[a12 * 128 + col1], s1);
    }
    q0 += __shfl_xor(q0, 16); q0 += __shfl_xor(q0, 32);
    q1 += __shfl_xor(q1, 16); q1 += __shfl_xor(q1, 32);
    if (l < 16) {
      int sb = (b == 2) ? ST_U2 : ST_V2;
      atomicAdd(&stats[sb + col0], q0);
      atomicAdd(&stats[sb + col1], q1);
    }
  }
  __syncthreads();

  // analytic bn3 sums
  {
    int c = t & 127, h = t >> 7;
    float dv0 = 0.f, dv1 = 0.f;
    for (int k = 0; k < 64; ++k) {
      float wk = W_3body[k * 128 + c];
      dv0 += xown[(2 * h) * 64 + k] * wk;
      dv1 += xown[(2 * h + 1) * 64 + k] * wk;
    }
    float b3v = b_3body[c];
    float pA = 0.f, pA2 = 0.f, pUb = 0.f, pVb = 0.f, pAU = 0.f, pAV = 0.f, pUV = 0.f;
#pragma unroll
    for (int aa = 0; aa < 2; ++aa) {
      int a = 2 * h + aa;
      float aval = (aa ? dv1 : dv0) + b3v;
      float ub = ubar[a * 128 + c] * (1.f / 12.f);
      float vb = vbar[a * 128 + c] * (1.f / 12.f);
      pA += aval; pA2 += aval * aval; pUb += ub; pVb += vb;
      pAU += aval * ub; pAV += aval * vb; pUV += ub * vb;
    }
    if (h == 1) {
      float* rs = &redscr[c * 7];
      rs[0] = pA; rs[1] = pA2; rs[2] = pUb; rs[3] = pVb; rs[4] = pAU; rs[5] = pAV; rs[6] = pUV;
    }
    __syncthreads();
    if (h == 0) {
      const float* rs = &redscr[c * 7];
      atomicAdd(&stats[ST_A + c], pA + rs[0]);
      atomicAdd(&stats[ST_A2 + c], pA2 + rs[1]);
      atomicAdd(&stats[ST_UB + c], pUb + rs[2]);
      atomicAdd(&stats[ST_VB + c], pVb + rs[3]);
      atomicAdd(&stats[ST_AU + c], pAU + rs[4]);
      atomicAdd(&stats[ST_AV + c], pAV + rs[5]);
      atomicAdd(&stats[ST_UV + c], pUV + rs[6]);
    }
  }
}

// ---------------- K3: finalize bn1/bne/bn3 affine params (sums replicas) ----------------
__global__ void k3_params(const float* __restrict__ stats_r,
                          const float* __restrict__ g1, const float* __restrict__ be1,
                          const float* __restrict__ ge, const float* __restrict__ bee,
                          const float* __restrict__ g3, const float* __restrict__ be3,
                          float* __restrict__ params) {
  __shared__ float ssum[STATSN];
  int c = threadIdx.x;
  for (int i = c; i < STATSN; i += 128) {
    float s = 0.f;
#pragma unroll
    for (int r = 0; r < REPL; ++r) s += stats_r[(size_t)r * STATSN + i];
    ssum[i] = s;
  }
  __syncthreads();
  if (c >= 128) return;
  const float* stats = ssum;
  const float cnt1 = 1.f / 96000.f;
  {
    float m = stats[ST_BN1S + c] * cnt1;
    float var = stats[ST_BN1S2 + c] * cnt1 - m * m;
    float s = g1[c] * rsqrtf(fmaxf(var, 0.f) + EPSV);
    params[c] = s; params[128 + c] = be1[c] - m * s;
  }
  {
    float m = stats[ST_BNES + c] * cnt1;
    float var = stats[ST_BNES2 + c] * cnt1 - m * m;
    float s = ge[c] * rsqrtf(fmaxf(var, 0.f) + EPSV);
    params[256 + c] = s; params[384 + c] = bee[c] - m * s;
  }
  {
    float Nf = (float)NATOMS;
    float A_ = stats[ST_A + c], A2 = stats[ST_A2 + c];
    float U2 = stats[ST_U2 + c], V2 = stats[ST_V2 + c];
    float Ub = stats[ST_UB + c], Vb = stats[ST_VB + c];
    float AU = stats[ST_AU + c], AV = stats[ST_AV + c], UV = stats[ST_UV + c];
    float m = (A_ + Ub + Vb) / Nf;
    float ez2 = A2 / Nf + (U2 + V2) / (Nf * 12.f) + 2.f * (AU + AV + UV) / Nf;
    float var = ez2 - m * m;
    float s = g3[c] * rsqrtf(fmaxf(var, 0.f) + EPSV);
    params[512 + c] = s; params[640 + c] = be3[c] - m * s;
  }
}

// ---------------- K4a: gates (b = 0,1) -> tbuf (two-body) + out_nbr ----------------
__global__ __launch_bounds__(256, 4) void k4a_main(const float* __restrict__ nbr_fea,
                                                   const int* __restrict__ nidx,
                                                   const float* __restrict__ b_full,
                                                   const float* __restrict__ b_edge,
                                                   const u16* __restrict__ PA,
                                                   const u16* __restrict__ WTE,
                                                   const float* __restrict__ params,
                                                   float* __restrict__ tbuf,
                                                   float* __restrict__ out_nbr) {
  __shared__ __align__(16) char smem[36608];
  short* nbrT     = (short*)smem;                 // 6144
  u16* paown0     = (u16*)(smem + 31488);
  u16* paown1     = (u16*)(smem + 32512);
  float* t2buf    = (float*)(smem + 33536);       // 1024
  float* params_s = (float*)(smem + 34560);       // 2048
  int t = threadIdx.x, l = t & 63, w = t >> 6;
  int ab = blockIdx.x * AB, eb = ab * 12;

  dma_pj2(PA, nidx, eb, smem + 6144, smem + 18816, 128, 384, w, l);
  if (w == 0) dma_own2(PA, paown0, paown1, ab, l);
  for (int u = t; u < ROWS * 4; u += 256) {
    int row = u >> 2, c16 = (u & 3) * 16;
    stage_row16(nbrT, row, c16, nbr_fea + (size_t)(eb + row) * 64 + c16);
  }
  params_s[t] = params[t];
  params_s[t + 256] = params[t + 256];
  t2buf[t] = 0.f;
  __syncthreads();

#pragma unroll
  for (int b = 0; b < 2; ++b) {
    const u16* stg = (const u16*)(smem + 6144 + b * STG_B);
    const u16* po = b ? paown1 : paown0;
    f32x4 acc[3][2];
    mfma_block<3>(nbrT, WTE, b, w, l, acc);
    int col0 = (w << 4) + (l & 15), col1 = col0 + 64;
    int g = l >> 4;
    const float* bp = b ? b_edge : b_full;
    float bias0 = bp[col0], bias1 = bp[col1];
    float sc0 = params_s[b * 256 + col0], sh0 = params_s[b * 256 + 128 + col0];
    float sc1 = params_s[b * 256 + col1], sh1 = params_s[b * 256 + 128 + col1];
#pragma unroll
    for (int rt = 0; rt < 3; ++rt) {
      int a12 = (rt * 16 + g * 4) / 12;
      float o0 = bf2f(po[a12 * 128 + col0]) + bias0;
      float o1 = bf2f(po[a12 * 128 + col1]) + bias1;
      float gsum = 0.f;
#pragma unroll
      for (int r = 0; r < 4; ++r) {
        int row = rt * 16 + g * 4 + r;
        float v0 = acc[rt][0][r] + bf2f(stg[stg_idx(row, col0)]) + o0;
        float v1 = acc[rt][1][r] + bf2f(stg[stg_idx(row, col1)]) + o1;
        float gate = sigf(v0 * sc0 + sh0) * spf(v1 * sc1 + sh1);
        if (b == 0) {
          gsum += gate;
        } else {
          size_t eg = (size_t)(eb + row) * 64 + col0;
          out_nbr[eg] = nbr_fea[eg] + gate;
        }
      }
      if (b == 0) atomicAdd(&t2buf[a12 * 64 + col0], gsum);
    }
  }
  __syncthreads();
  tbuf[(size_t)(ab + w) * 64 + l] = t2buf[t];
}

// ---------------- K4b: 3-body (b = 2,3) + bn2 stats ----------------
__global__ __launch_bounds__(256, 4) void k4b_main(const float* __restrict__ atom_in,
                                                   const float* __restrict__ nbr_fea,
                                                   const int* __restrict__ nidx,
                                                   const float* __restrict__ W_3body,
                                                   const float* __restrict__ b_3body,
                                                   const u16* __restrict__ PA,
                                                   const u16* __restrict__ WTE,
                                                   const float* __restrict__ params,
                                                   float* __restrict__ tbuf,
                                                   float* __restrict__ stats_r) {
  __shared__ __align__(16) char smem[35584];
  short* nbrT    = (short*)smem;                 // 6144
  u16* stage2    = (u16*)(smem + 6144);
  u16* stage3    = (u16*)(smem + 18816);
  float* a_s     = (float*)(smem + 31488);       // 2048
  float* xown    = (float*)(smem + 33536);       // 1024
  float* p3_s    = (float*)(smem + 34560);       // 1024: s3[0:128) t3[128:256)
  float* redscr2 = (float*)(smem + 6144);        // alias stage2 (final phase only)
  int t = threadIdx.x, l = t & 63, w = t >> 6;
  int ab = blockIdx.x * AB, eb = ab * 12;
  float* stats = stats_r + (size_t)(blockIdx.x & (REPL - 1)) * STATSN;

  dma_pj2(PA, nidx, eb, smem + 6144, smem + 18816, 512, 640, w, l);
  for (int u = t; u < ROWS * 4; u += 256) {
    int row = u >> 2, c16 = (u & 3) * 16;
    stage_row16(nbrT, row, c16, nbr_fea + (size_t)(eb + row) * 64 + c16);
  }
  xown[t] = atom_in[(size_t)ab * 64 + t];
  p3_s[t] = params[512 + t];
  float two_body = tbuf[(size_t)(ab + w) * 64 + l];
  __syncthreads();

  // a' = (x_i @ Wa + b3) * s3 + t3 (f32)
  {
    int c = t & 127, h = t >> 7;
    float dv0 = 0.f, dv1 = 0.f;
    for (int k = 0; k < 64; ++k) {
      float wk = W_3body[k * 128 + c];
      dv0 += xown[(2 * h) * 64 + k] * wk;
      dv1 += xown[(2 * h + 1) * 64 + k] * wk;
    }
    float s3 = p3_s[c], t3 = p3_s[128 + c];
    float b3v = b_3body[c];
    a_s[(2 * h) * 128 + c] = (dv0 + b3v) * s3 + t3;
    a_s[(2 * h + 1) * 128 + c] = (dv1 + b3v) * s3 + t3;
  }

#pragma unroll
  for (int b = 2; b < 4; ++b) {
    u16* stg = (b == 2) ? stage2 : stage3;
    f32x4 acc[3][2];
    mfma_block<3>(nbrT, WTE, b, w, l, acc);
    int col0 = (w << 4) + (l & 15), col1 = col0 + 64;
    int g = l >> 4;
    float s30 = p3_s[col0], s31 = p3_s[col1];
#pragma unroll
    for (int rt = 0; rt < 3; ++rt) {
#pragma unroll
      for (int r = 0; r < 4; ++r) {
        int row = rt * 16 + g * 4 + r;
        float v0 = (acc[rt][0][r] + bf2f(stg[stg_idx(row, col0)])) * s30;
        float v1 = (acc[rt][1][r] + bf2f(stg[stg_idx(row, col1)])) * s31;
        stg[stg_idx(row, col0)] = f2bf(v0);
        stg[stg_idx(row, col1)] = f2bf(v1);
      }
    }
  }
  __syncthreads();

  // 3-body via exp factorization: sig(a+u+v) = rcp(1+E*F), sp = ln2*log2(1+G*H)
  float acc3 = 0.f;
  {
    int c = l, a = w;
    float af = a_s[a * 128 + c], ac = a_s[a * 128 + 64 + c];
    float Fl[12], Hl[12];
#pragma unroll
    for (int j2 = 0; j2 < 12; ++j2) {
      float vf = bf2f(stage3[stg_idx(a * 12 + j2, c)]);
      float vc = bf2f(stage3[stg_idx(a * 12 + j2, 64 + c)]);
      Fl[j2] = __expf(-vf);
      Hl[j2] = __expf(vc);
    }
    for (int j = 0; j < 12; ++j) {
      float uf = bf2f(stage2[stg_idx(a * 12 + j, c)]);
      float uc = bf2f(stage2[stg_idx(a * 12 + j, 64 + c)]);
      float Ej = __expf(-(af + uf));
      float Gj = __expf(ac + uc);
#pragma unroll
      for (int l2 = 0; l2 < 12; ++l2) {
        float p = fmaf(Ej, Fl[l2], 1.f);
        float q = fmaf(Gj, Hl[l2], 1.f);
        acc3 += __builtin_amdgcn_rcpf(p) * __log2f(q);
      }
    }
  }
  __syncthreads();

  // t = two + three body; bn2 partial sums
  {
    float x = two_body + acc3 * 0.6931471805599453f;
    tbuf[(size_t)(ab + w) * 64 + l] = x;
    redscr2[t] = x;
    redscr2[256 + t] = x * x;
    __syncthreads();
    if (t < 64) {
      float s = redscr2[t] + redscr2[t + 64] + redscr2[t + 128] + redscr2[t + 192];
      float s2 = redscr2[256 + t] + redscr2[256 + t + 64] + redscr2[256 + t + 128] + redscr2[256 + t + 192];
      atomicAdd(&stats[ST_BN2S + t], s);
      atomicAdd(&stats[ST_BN2S2 + t], s2);
    }
  }
}

// ---------------- K6: bn2 + final softplus (sums replicas) ----------------
__global__ __launch_bounds__(256) void k6_out(const float* __restrict__ atom_in,
                                              const float* __restrict__ tbuf,
                                              const float* __restrict__ stats_r,
                                              const float* __restrict__ g2,
                                              const float* __restrict__ be2,
                                              float* __restrict__ out_atom) {
  __shared__ float sc[64], sh[64];
  int t = threadIdx.x;
  if (t < 64) {
    float S = 0.f, S2 = 0.f;
#pragma unroll
    for (int r = 0; r < REPL; ++r) {
      S += stats_r[(size_t)r * STATSN + ST_BN2S + t];
      S2 += stats_r[(size_t)r * STATSN + ST_BN2S2 + t];
    }
    float m = S * (1.f / (float)NATOMS);
    float var = S2 * (1.f / (float)NATOMS) - m * m;
    float s = g2[t] * rsqrtf(fmaxf(var, 0.f) + EPSV);
    sc[t] = s; sh[t] = be2[t] - m * s;
  }
  __syncthreads();
  int i = blockIdx.x * 256 + t;
  if (i < NATOMS * 64) {
    int c = i & 63;
    float v = atom_in[i] + tbuf[i] * sc[c] + sh[c];
    out_atom[i] = spf(v);
  }
}

extern "C" void kernel_launch(void* const* d_in, const int* in_sizes, int n_in,
                              void* d_out, int out_size, void* d_ws, size_t ws_size,
                              hipStream_t stream) {
  if (ws_size < (size_t)WS_NEED) return;
  const float* atom_in = (const float*)d_in[0];
  const float* nbr_fea = (const float*)d_in[1];
  const int* nidx = (const int*)d_in[2];
  const float* W_full = (const float*)d_in[3];
  const float* b_full = (const float*)d_in[4];
  const float* g1 = (const float*)d_in[5];
  const float* be1 = (const float*)d_in[6];
  const float* W_edge = (const float*)d_in[7];
  const float* b_edge = (const float*)d_in[8];
  const float* ge = (const float*)d_in[9];
  const float* bee = (const float*)d_in[10];
  const float* W_3body = (const float*)d_in[11];
  const float* b_3body = (const float*)d_in[12];
  const float* g3 = (const float*)d_in[13];
  const float* be3 = (const float*)d_in[14];
  const float* g2 = (const float*)d_in[15];
  const float* be2 = (const float*)d_in[16];

  char* ws = (char*)d_ws;
  u16* PA = (u16*)(ws + PA_OFF);
  u16* WTA = (u16*)(ws + WTA_OFF);
  u16* WTE = (u16*)(ws + WTE_OFF);
  float* stats = (float*)(ws + STATS_OFF);
  float* params = (float*)(ws + PARAMS_OFF);
  float* tbuf = (float*)(ws + TBUF_OFF);

  float* out_atom = (float*)d_out;
  float* out_nbr = out_atom + NATOMS * 64;

  k0_prep<<<320, 256, 0, stream>>>(W_full, W_edge, W_3body, WTA, WTE, stats);
  k1_pa<<<500, 256, 0, stream>>>(atom_in, WTA, PA);
  k2a_stats<<<2000, 256, 0, stream>>>(nbr_fea, nidx, b_full, b_edge, PA, WTE, stats);
  k2b_stats<<<2000, 256, 0, stream>>>(atom_in, nbr_fea, nidx, W_3body, b_3body, PA, WTE, stats);
  k3_params<<<1, 128, 0, stream>>>(stats, g1, be1, ge, bee, g3, be3, params);
  k4a_main<<<2000, 256, 0, stream>>>(nbr_fea, nidx, b_full, b_edge, PA, WTE, params, tbuf, out_nbr);
  k4b_main<<<2000, 256, 0, stream>>>(atom_in, nbr_fea, nidx, W_3body, b_3body, PA, WTE, params,
                                     tbuf, stats);
  k6_out<<<2000, 256, 0, stream>>>(atom_in, tbuf, stats, g2, be2, out_atom);
}